// Round 4
// baseline (6097.014 us; speedup 1.0000x reference)
//
#include <hip/hip_runtime.h>

typedef unsigned short u16;
typedef unsigned int u32;
typedef unsigned long long u64;
typedef __attribute__((ext_vector_type(8))) short bf16x8;
typedef __attribute__((ext_vector_type(4))) float f32x4;
typedef __attribute__((ext_vector_type(4))) _Float16 f16x4;

#define MFMA16(a, b, c) __builtin_amdgcn_mfma_f32_16x16x32_bf16((a), (b), (c), 0, 0, 0)

__device__ __forceinline__ u16 f2bf(float f) {
    union { float f; u32 u; } v; v.f = f;
    u32 r = v.u + 0x7FFFu + ((v.u >> 16) & 1u);
    return (u16)(r >> 16);
}
__device__ __forceinline__ float sigmoidf_(float x) {
    return 1.0f / (1.0f + __expf(-x));
}
__device__ __forceinline__ float tanhf_(float x) {
    float e = __expf(-2.0f * x);
    return (1.0f - e) / (1.0f + e);
}

// ---------------- mask: mask[row] = any(X[row, :512] != 0) ----------------
__global__ void mask_kernel(const float* __restrict__ X, int* __restrict__ mask) {
    int row = blockIdx.x;
    int lane = threadIdx.x;
    const float* r = X + (size_t)row * 512;
    int nz = 0;
    #pragma unroll
    for (int i = 0; i < 8; ++i) nz |= (r[lane + 64 * i] != 0.0f);
    nz = __any(nz);
    if (lane == 0) mask[row] = nz ? 1 : 0;
}

// ---------------- cast fp32 -> bf16 (4 elems/thread) ----------------
__global__ void cast_bf16_kernel(const float* __restrict__ in, u16* __restrict__ out, int n) {
    int i = (blockIdx.x * blockDim.x + threadIdx.x) * 4;
    if (i + 3 < n) {
        float4 v = *(const float4*)(in + i);
        u32 a = (u32)f2bf(v.x) | ((u32)f2bf(v.y) << 16);
        u32 b = (u32)f2bf(v.z) | ((u32)f2bf(v.w) << 16);
        *(uint2*)(out + i) = make_uint2(a, b);
    }
}

// ---------------- transpose + cast: in fp32 [K][N] -> out bf16 [N][K] ----------------
__global__ void transpose_cast_kernel(const float* __restrict__ in, u16* __restrict__ out,
                                      int K, int N) {
    __shared__ float tile[32][33];
    int k0 = blockIdx.y * 32, n0 = blockIdx.x * 32;
    int tx = threadIdx.x, ty = threadIdx.y;
    #pragma unroll
    for (int i = ty; i < 32; i += 8)
        tile[i][tx] = in[(size_t)(k0 + i) * N + (n0 + tx)];
    __syncthreads();
    #pragma unroll
    for (int i = ty; i < 32; i += 8)
        out[(size_t)(n0 + i) * K + (k0 + tx)] = f2bf(tile[tx][i]);
}

// ---------------- GEMM: xz = A @ Bt^T + bias, output in rec-friendly layout ----------
// C element index: (((t*32 + slice)*64 + b)*16 + dcol)*4 + g   (fp16)
// where m-row = b*256+t, n-col = g*512 + slice*16 + dcol.
__global__ __launch_bounds__(256) void gemm_xz_kernel(
        const u16* __restrict__ A, const u16* __restrict__ Bt,
        const float* __restrict__ bias, _Float16* __restrict__ C, int K) {
    int w = threadIdx.x >> 6, lane = threadIdx.x & 63;
    int q = lane >> 4, col = lane & 15;
    int m0 = blockIdx.x * 64 + w * 16;
    int n0 = blockIdx.y * 64;

    const u16* arow = A + (size_t)(m0 + col) * K + q * 8;
    f32x4 acc[4];
    #pragma unroll
    for (int nt = 0; nt < 4; ++nt) acc[nt] = (f32x4){0.f, 0.f, 0.f, 0.f};

    for (int kc = 0; kc < K; kc += 32) {
        bf16x8 a = *(const bf16x8*)(arow + kc);
        #pragma unroll
        for (int nt = 0; nt < 4; ++nt) {
            bf16x8 b = *(const bf16x8*)(Bt + (size_t)(n0 + nt * 16 + col) * K + kc + q * 8);
            acc[nt] = MFMA16(a, b, acc[nt]);
        }
    }
    #pragma unroll
    for (int nt = 0; nt < 4; ++nt) {
        int n = n0 + nt * 16 + col;
        int g = n >> 9, d = n & 511;
        float bs = bias[n];
        #pragma unroll
        for (int r = 0; r < 4; ++r) {
            int row = m0 + q * 4 + r;
            int b = row >> 8, t = row & 255;
            size_t idx = ((((size_t)t * 32 + (d >> 4)) * 64 + b) * 16 + (d & 15)) * 4 + g;
            C[idx] = (_Float16)(acc[nt][r] + bs);
        }
    }
}

// ---------------- zero-init (flags) ----------------
__global__ void init_rec_kernel(u32* __restrict__ p, int n) {
    int i = blockIdx.x * 256 + threadIdx.x;
    if (i < n) p[i] = 0;
}

// ---------------- persistent d-sliced LSTM recurrence, v12 ----------------
// grid (32 slices, 2 dirs) x 256 thr (4 waves). Block owns 16 h-dims x 4 gates.
// R13 changes vs rec11 (protocol instructions IDENTICAL; only scheduling):
//  (a) y stores deferred ONE iteration: issued after the next poll succeeds and
//      AFTER the h loads are issued. vmcnt is an in-order counter, so in rec11
//      the poll's flag-load consumption stalled on the 4 NT HBM y-store ACKs
//      issued just before (the drain moved, not removed). Now the y-ACK
//      overlaps h-load RT + MFMA + gates; afr waits leave the (newer) stores
//      outstanding.
//  (b) 3-deep pipelined flag poll: 3 independent in-flight flag loads, check
//      oldest, reissue one per check -> detect granularity ~RT/3 instead of
//      RT+sleep. Self-pacing via vmcnt (cannot spin faster than loads return),
//      so poll traffic is only ~3x rec11's (tiny vs rec10's data-poll volume).
// Safety (per plane w, unchanged): flag_{w,s} >= k certifies wave w of block s
//   published h^k (vmcnt(0) drain of its 2 WT stores precedes the flag store)
//   AND consumed slot (k-1)&1. Step 0 consumes zero-registers (no hg init).
__global__ __launch_bounds__(256) void lstm_rec12_kernel(
        const _Float16* __restrict__ xz_f, const _Float16* __restrict__ xz_b,
        const u16* __restrict__ Ut_f, const u16* __restrict__ Ut_b,
        const int* __restrict__ mask,
        u32* __restrict__ flags,    // [dir*128 + wave*32 + slice] monotone counters
        u16* __restrict__ hg,       // [slot][dir][64][512] bf16, slot stride 65536
        u16* __restrict__ y_bf,     // layer1 out (null for layer2)
        float* __restrict__ y_f32,  // layer2 H out (null for layer1)
        float* __restrict__ hc_out) // layer2 hidden @0, cell @65536 (null for layer1)
{
    const int T = 256;
    int slice = blockIdx.x, dir = blockIdx.y;
    int tid = threadIdx.x;
    int lane = tid & 63, q = lane >> 4, col = lane & 15;
    int wv = tid >> 6;
    int ds = slice * 16, m0 = wv * 16;

    const _Float16* xz = dir ? xz_b : xz_f;
    const u16* Ut = dir ? Ut_b : Ut_f;
    u32* planeflags = flags + dir * 128 + wv * 32;   // this plane's 32 flags
    u32* myflag = planeflags + slice;
    const u32* pf = planeflags + (lane & 31);

    // ---- stage U-slice into LDS once, per-fragment contiguous ----
    // cell = (g*16+kc)*64 + l; holds U[g*512+ds+(l&15)][kc*32+(l>>4)*8 ..+8].
    alignas(16) __shared__ u16 Ulds[4 * 16 * 64 * 8];  // 64 KB
    for (int cell = tid; cell < 4096; cell += 256) {
        int l = cell & 63, fr = cell >> 6;
        int kc = fr & 15, g = fr >> 4;
        *(uint4*)&Ulds[cell * 8] =
            *(const uint4*)(Ut + (size_t)(g * 512 + ds + (l & 15)) * 512 + kc * 32 + (l >> 4) * 8);
    }

    float creg[4] = {0.f, 0.f, 0.f, 0.f};
    float hreg[4] = {0.f, 0.f, 0.f, 0.f};
    u32 phb[4] = {0, 0, 0, 0};          // deferred y: prev step's bf16 bits
    float pyf[4] = {0.f, 0.f, 0.f, 0.f}; // deferred y: prev step's f32 values
    int pt = 0;                          // deferred y: prev step's t
    __syncthreads();   // Ulds cross-wave staging only; no barriers inside the loop

    for (int it = 0; it < T; ++it) {
        int t = dir ? (T - 1 - it) : it;
        const u16* hsrc = hg + (it & 1) * 65536 + dir * 32768;
        u16* hdst = hg + ((it & 1) ^ 1) * 65536 + dir * 32768;

        // xz + mask loads for this step (independent of h) — issued before the poll
        f16x4 xzv[4];
        {
            const _Float16* xzt = xz + (((size_t)t * 32 + slice) * 64) * 64;
            #pragma unroll
            for (int r = 0; r < 4; ++r)
                xzv[r] = *(const f16x4*)(xzt + ((m0 + q * 4 + r) * 16 + col) * 4);
        }
        int mk[4];
        #pragma unroll
        for (int r = 0; r < 4; ++r) mk[r] = mask[(m0 + q * 4 + r) * T + t];

        // ---- poll this plane's 32 producer flags (3-deep pipelined), then load h ----
        bf16x8 afr[16];
        if (it == 0) {
            #pragma unroll
            for (int c = 0; c < 16; ++c)
                afr[c] = (bf16x8){0, 0, 0, 0, 0, 0, 0, 0};
        } else {
            u32 tgt = (u32)it;
            u32 f0 = __hip_atomic_load(pf, __ATOMIC_RELAXED, __HIP_MEMORY_SCOPE_AGENT);
            u32 f1 = __hip_atomic_load(pf, __ATOMIC_RELAXED, __HIP_MEMORY_SCOPE_AGENT);
            u32 f2 = __hip_atomic_load(pf, __ATOMIC_RELAXED, __HIP_MEMORY_SCOPE_AGENT);
            for (;;) {
                if (__builtin_expect(__all(f0 >= tgt), 1)) break;
                f0 = f1; f1 = f2;
                f2 = __hip_atomic_load(pf, __ATOMIC_RELAXED, __HIP_MEMORY_SCOPE_AGENT);
            }
            __builtin_amdgcn_sched_barrier(0);  // pin h loads after the poll
            const u64* hp = (const u64*)(hsrc + (size_t)(m0 + col) * 512 + q * 8);
            #pragma unroll
            for (int c = 0; c < 16; ++c) {
                union { u64 qw[2]; bf16x8 v; } u;
                u.qw[0] = __hip_atomic_load(hp + c * 8, __ATOMIC_RELAXED,
                                            __HIP_MEMORY_SCOPE_AGENT);
                u.qw[1] = __hip_atomic_load(hp + c * 8 + 1, __ATOMIC_RELAXED,
                                            __HIP_MEMORY_SCOPE_AGENT);
                afr[c] = u.v;
            }
            // ---- deferred y stores of step it-1, issued AFTER (newer than) the
            //      h loads: afr consumption waits leave them outstanding; their
            //      HBM ACK overlaps h-load RT + MFMA + gates.
            __builtin_amdgcn_sched_barrier(0);  // keep stores below the h loads
            #pragma unroll
            for (int r = 0; r < 4; ++r) {
                int b = m0 + q * 4 + r;
                size_t ybase = ((size_t)b * T + pt) * 1024 + dir * 512 + ds + col;
                if (y_bf) __builtin_nontemporal_store((u16)phb[r], y_bf + ybase);
                else      __builtin_nontemporal_store(pyf[r], y_f32 + ybase);
            }
        }

        // ---- z = h @ U for 4 gates x 16 dims x wave's 16 rows ----
        f32x4 acc[4];
        #pragma unroll
        for (int g = 0; g < 4; ++g) acc[g] = (f32x4){0.f, 0.f, 0.f, 0.f};
        #pragma unroll
        for (int kc = 0; kc < 16; ++kc) {
            #pragma unroll
            for (int g = 0; g < 4; ++g) {
                bf16x8 b = *(const bf16x8*)&Ulds[((g * 16 + kc) * 64 + lane) * 8];
                acc[g] = MFMA16(afr[kc], b, acc[g]);
            }
        }

        // ---- gates, state update ----
        u32 hbv[4];
        #pragma unroll
        for (int r = 0; r < 4; ++r) {
            float zi = acc[0][r] + (float)xzv[r][0];
            float zf = acc[1][r] + (float)xzv[r][1];
            float zg = acc[2][r] + (float)xzv[r][2];
            float zo = acc[3][r] + (float)xzv[r][3];
            float ig = sigmoidf_(zi);
            float fg = sigmoidf_(zf);
            float gg = tanhf_(zg);
            float og = sigmoidf_(zo);
            float cn = fg * creg[r] + ig * gg;
            float hn = og * tanhf_(cn);
            if (mk[r]) { creg[r] = cn; hreg[r] = hn; }
            hbv[r] = (u32)f2bf(hreg[r]);
        }

        // ---- publish h^{it+1}: pack dim pairs via shfl, WT u32 agent stores,
        //      per-wave drain, per-wave flag.
        if (it < T - 1) {
            u32 part[4];
            #pragma unroll
            for (int r = 0; r < 4; ++r) part[r] = (u32)__shfl_xor((int)hbv[r], 1);
            int odd = col & 1;
            u32 p0 = odd ? (part[2] | (hbv[2] << 16)) : (hbv[0] | (part[0] << 16));
            u32 p1 = odd ? (part[3] | (hbv[3] << 16)) : (hbv[1] | (part[1] << 16));
            int r0 = q * 4 + (odd ? 2 : 0);
            u32* w0 = (u32*)(hdst + (size_t)(m0 + r0) * 512 + ds + (col & ~1));
            u32* w1 = (u32*)(hdst + (size_t)(m0 + r0 + 1) * 512 + ds + (col & ~1));
            __hip_atomic_store(w0, p0, __ATOMIC_RELAXED, __HIP_MEMORY_SCOPE_AGENT);
            __hip_atomic_store(w1, p1, __ATOMIC_RELAXED, __HIP_MEMORY_SCOPE_AGENT);
            // drain this wave's WT stores (+ this iteration's y stores, which
            // have had h-RT + MFMA + gates to retire), then fire the flag.
            asm volatile("s_waitcnt vmcnt(0)" ::: "memory");
            if (lane == 0)
                __hip_atomic_store(myflag, (u32)(it + 1), __ATOMIC_RELAXED,
                                   __HIP_MEMORY_SCOPE_AGENT);
        }

        // ---- stash this step's y for deferred store next iteration ----
        pt = t;
        #pragma unroll
        for (int r = 0; r < 4; ++r) { phb[r] = hbv[r]; pyf[r] = hreg[r]; }
    }

    // ---- tail: flush the last step's deferred y ----
    #pragma unroll
    for (int r = 0; r < 4; ++r) {
        int b = m0 + q * 4 + r;
        size_t ybase = ((size_t)b * T + pt) * 1024 + dir * 512 + ds + col;
        if (y_bf) __builtin_nontemporal_store((u16)phb[r], y_bf + ybase);
        else      __builtin_nontemporal_store(pyf[r], y_f32 + ybase);
    }

    if (hc_out) {
        #pragma unroll
        for (int r = 0; r < 4; ++r) {
            int b = m0 + q * 4 + r;
            hc_out[(size_t)b * 1024 + dir * 512 + ds + col] = hreg[r];
            hc_out[65536 + (size_t)b * 1024 + dir * 512 + ds + col] = creg[r];
        }
    }
}

extern "C" void kernel_launch(void* const* d_in, const int* in_sizes, int n_in,
                              void* d_out, int out_size, void* d_ws, size_t ws_size,
                              hipStream_t stream) {
    const float* X   = (const float*)d_in[0];
    const float* Wf1 = (const float*)d_in[1];
    const float* Uf1 = (const float*)d_in[2];
    const float* bf1 = (const float*)d_in[3];
    const float* Wb1 = (const float*)d_in[4];
    const float* Ub1 = (const float*)d_in[5];
    const float* bb1 = (const float*)d_in[6];
    const float* Wf2 = (const float*)d_in[7];
    const float* Uf2 = (const float*)d_in[8];
    const float* bf2 = (const float*)d_in[9];
    const float* Wb2 = (const float*)d_in[10];
    const float* Ub2 = (const float*)d_in[11];
    const float* bb2 = (const float*)d_in[12];
    float* out = (float*)d_out;

    // scratch carved from d_out's H region (67.1 MB, dead until layer-2 rec):
    // y1bf 33.55 MB @0, Xbf 16.78 MB after; both consumed by layer-2 GEMMs (stream order).
    u16* y1bf = (u16*)d_out;
    u16* Xbf  = (u16*)((char*)d_out + 33554432);

    char* ws = (char*)d_ws;
    size_t off = 0;
    auto alloc = [&](size_t bytes) { char* p = ws + off; off = (off + bytes + 255) & ~(size_t)255; return p; };
    u16*  Wt1f  = (u16*)alloc(2048ull * 512 * 2);
    u16*  Wt1b  = (u16*)alloc(2048ull * 512 * 2);
    u16*  Wt2f  = (u16*)alloc(2048ull * 1024 * 2);
    u16*  Wt2b  = (u16*)alloc(2048ull * 1024 * 2);
    u16*  Ut1f  = (u16*)alloc(2048ull * 512 * 2);
    u16*  Ut1b  = (u16*)alloc(2048ull * 512 * 2);
    u16*  Ut2f  = (u16*)alloc(2048ull * 512 * 2);
    u16*  Ut2b  = (u16*)alloc(2048ull * 512 * 2);
    int*  maskb = (int*)alloc(16384ull * 4);
    // per-wave flags: 2 dirs x 4 waves x 32 slices = 256 u32 (1 KB)
    u32*  flags = (u32*)alloc(1024);
    // h exchange: 2 slots x 2 dirs x 64 x 512 bf16 = 256 KB (never read before
    // write: step 0 consumes zero registers, so no zero-init needed)
    u16*  hg    = (u16*)alloc(2ull * 2 * 64 * 512 * 2);
    _Float16* xzf = (_Float16*)alloc(16384ull * 2048 * 2);
    _Float16* xzb = (_Float16*)alloc(16384ull * 2048 * 2);
    (void)ws_size; (void)in_sizes; (void)n_in; (void)out_size;
    const int initN = 256;  // flag words only

    // prep
    mask_kernel<<<dim3(16384), dim3(64), 0, stream>>>(X, maskb);
    cast_bf16_kernel<<<dim3(8192), dim3(256), 0, stream>>>(X, Xbf, 16384 * 512);
    transpose_cast_kernel<<<dim3(64, 16), dim3(32, 8), 0, stream>>>(Wf1, Wt1f, 512, 2048);
    transpose_cast_kernel<<<dim3(64, 16), dim3(32, 8), 0, stream>>>(Wb1, Wt1b, 512, 2048);
    transpose_cast_kernel<<<dim3(64, 32), dim3(32, 8), 0, stream>>>(Wf2, Wt2f, 1024, 2048);
    transpose_cast_kernel<<<dim3(64, 32), dim3(32, 8), 0, stream>>>(Wb2, Wt2b, 1024, 2048);
    transpose_cast_kernel<<<dim3(64, 16), dim3(32, 8), 0, stream>>>(Uf1, Ut1f, 512, 2048);
    transpose_cast_kernel<<<dim3(64, 16), dim3(32, 8), 0, stream>>>(Ub1, Ut1b, 512, 2048);
    transpose_cast_kernel<<<dim3(64, 16), dim3(32, 8), 0, stream>>>(Uf2, Ut2f, 512, 2048);
    transpose_cast_kernel<<<dim3(64, 16), dim3(32, 8), 0, stream>>>(Ub2, Ut2b, 512, 2048);

    // layer 1
    gemm_xz_kernel<<<dim3(256, 32), dim3(256), 0, stream>>>(Xbf, Wt1f, bf1, xzf, 512);
    gemm_xz_kernel<<<dim3(256, 32), dim3(256), 0, stream>>>(Xbf, Wt1b, bb1, xzb, 512);
    init_rec_kernel<<<dim3(1), dim3(256), 0, stream>>>(flags, initN);
    lstm_rec12_kernel<<<dim3(32, 2), dim3(256), 0, stream>>>(
        xzf, xzb, Ut1f, Ut1b, maskb, flags, hg, y1bf, nullptr, nullptr);

    // layer 2
    gemm_xz_kernel<<<dim3(256, 32), dim3(256), 0, stream>>>(y1bf, Wt2f, bf2, xzf, 1024);
    gemm_xz_kernel<<<dim3(256, 32), dim3(256), 0, stream>>>(y1bf, Wt2b, bb2, xzb, 1024);
    init_rec_kernel<<<dim3(1), dim3(256), 0, stream>>>(flags, initN);
    lstm_rec12_kernel<<<dim3(32, 2), dim3(256), 0, stream>>>(
        xzf, xzb, Ut2f, Ut2b, maskb, flags, hg, nullptr, out, out + 16777216);
}

// Round 5
// 4798.293 us; speedup vs baseline: 1.2707x; 1.2707x over previous
//
#include <hip/hip_runtime.h>

typedef unsigned short u16;
typedef unsigned int u32;
typedef unsigned long long u64;
typedef __attribute__((ext_vector_type(8))) short bf16x8;
typedef __attribute__((ext_vector_type(4))) float f32x4;
typedef __attribute__((ext_vector_type(4))) _Float16 f16x4;

#define MFMA16(a, b, c) __builtin_amdgcn_mfma_f32_16x16x32_bf16((a), (b), (c), 0, 0, 0)

__device__ __forceinline__ u16 f2bf(float f) {
    union { float f; u32 u; } v; v.f = f;
    u32 r = v.u + 0x7FFFu + ((v.u >> 16) & 1u);
    return (u16)(r >> 16);
}
__device__ __forceinline__ float sigmoidf_(float x) {
    return 1.0f / (1.0f + __expf(-x));
}
__device__ __forceinline__ float tanhf_(float x) {
    float e = __expf(-2.0f * x);
    return (1.0f - e) / (1.0f + e);
}

// ---------------- mask: mask[row] = any(X[row, :512] != 0) ----------------
__global__ void mask_kernel(const float* __restrict__ X, int* __restrict__ mask) {
    int row = blockIdx.x;
    int lane = threadIdx.x;
    const float* r = X + (size_t)row * 512;
    int nz = 0;
    #pragma unroll
    for (int i = 0; i < 8; ++i) nz |= (r[lane + 64 * i] != 0.0f);
    nz = __any(nz);
    if (lane == 0) mask[row] = nz ? 1 : 0;
}

// ---------------- cast fp32 -> bf16 (4 elems/thread) ----------------
__global__ void cast_bf16_kernel(const float* __restrict__ in, u16* __restrict__ out, int n) {
    int i = (blockIdx.x * blockDim.x + threadIdx.x) * 4;
    if (i + 3 < n) {
        float4 v = *(const float4*)(in + i);
        u32 a = (u32)f2bf(v.x) | ((u32)f2bf(v.y) << 16);
        u32 b = (u32)f2bf(v.z) | ((u32)f2bf(v.w) << 16);
        *(uint2*)(out + i) = make_uint2(a, b);
    }
}

// ---------------- transpose + cast: in fp32 [K][N] -> out bf16 [N][K] ----------------
__global__ void transpose_cast_kernel(const float* __restrict__ in, u16* __restrict__ out,
                                      int K, int N) {
    __shared__ float tile[32][33];
    int k0 = blockIdx.y * 32, n0 = blockIdx.x * 32;
    int tx = threadIdx.x, ty = threadIdx.y;
    #pragma unroll
    for (int i = ty; i < 32; i += 8)
        tile[i][tx] = in[(size_t)(k0 + i) * N + (n0 + tx)];
    __syncthreads();
    #pragma unroll
    for (int i = ty; i < 32; i += 8)
        out[(size_t)(n0 + i) * K + (k0 + tx)] = f2bf(tile[tx][i]);
}

// ---------------- GEMM: xz = A @ Bt^T + bias, gate-fused n-tiling ----------
// R14: block covers ONE dim-slice x ALL 4 gates: n(g) = g*512 + slice*16 + col.
// Each lane then holds the 4 gate values for its (row, dcol) -- exactly the 4
// contiguous f16 of the xz layout -- so the epilogue is ONE u64 store per row
// (was 16 scattered 2-B stores at 25% line utilization).
// C element index unchanged: (((t*32 + slice)*64 + b)*16 + dcol)*4 + g.
__global__ __launch_bounds__(256) void gemm_xz_kernel(
        const u16* __restrict__ A, const u16* __restrict__ Bt,
        const float* __restrict__ bias, _Float16* __restrict__ C, int K) {
    int w = threadIdx.x >> 6, lane = threadIdx.x & 63;
    int q = lane >> 4, col = lane & 15;
    int m0 = blockIdx.x * 64 + w * 16;
    int sl = blockIdx.y;  // dim-slice 0..31

    const u16* arow = A + (size_t)(m0 + col) * K + q * 8;
    const u16* brow0 = Bt + (size_t)(0 * 512 + sl * 16 + col) * K + q * 8;
    const u16* brow1 = Bt + (size_t)(1 * 512 + sl * 16 + col) * K + q * 8;
    const u16* brow2 = Bt + (size_t)(2 * 512 + sl * 16 + col) * K + q * 8;
    const u16* brow3 = Bt + (size_t)(3 * 512 + sl * 16 + col) * K + q * 8;
    f32x4 acc[4];
    #pragma unroll
    for (int g = 0; g < 4; ++g) acc[g] = (f32x4){0.f, 0.f, 0.f, 0.f};

    for (int kc = 0; kc < K; kc += 32) {
        bf16x8 a = *(const bf16x8*)(arow + kc);
        acc[0] = MFMA16(a, *(const bf16x8*)(brow0 + kc), acc[0]);
        acc[1] = MFMA16(a, *(const bf16x8*)(brow1 + kc), acc[1]);
        acc[2] = MFMA16(a, *(const bf16x8*)(brow2 + kc), acc[2]);
        acc[3] = MFMA16(a, *(const bf16x8*)(brow3 + kc), acc[3]);
    }

    float bs[4];
    #pragma unroll
    for (int g = 0; g < 4; ++g) bs[g] = bias[g * 512 + sl * 16 + col];

    #pragma unroll
    for (int r = 0; r < 4; ++r) {
        int row = m0 + q * 4 + r;
        int b = row >> 8, t = row & 255;
        union { _Float16 h[4]; u64 u; } pk;
        #pragma unroll
        for (int g = 0; g < 4; ++g) pk.h[g] = (_Float16)(acc[g][r] + bs[g]);
        size_t uidx = (((size_t)t * 32 + sl) * 64 + b) * 16 + col;
        ((u64*)C)[uidx] = pk.u;
    }
}

// ---------------- zero-init (flags) ----------------
__global__ void init_rec_kernel(u32* __restrict__ p, int n) {
    int i = blockIdx.x * 256 + threadIdx.x;
    if (i < n) p[i] = 0;
}

// ---------------- persistent d-sliced LSTM recurrence, v11: per-wave flags ---------
// (verbatim revert to the round-3 kernel that measured 1540 us/dispatch; rec12's
//  deferred-y + pipelined-poll experiment regressed and is abandoned.)
// grid (32 slices, 2 dirs) x 256 thr (4 waves). Block owns 16 h-dims x 4 gates.
//   (a) y stores after the flag publish; their HBM ACK drains during the next
//       step's poll wait, which is concurrent with waiting for producers.
//   (b) per-WAVE flags: exchange partitioned into 4 row-planes (producer wave w
//       writes rows 16w..16w+15; consumer wave w reads exactly those rows), so
//       each wave drains its own 2 WT stores and fires its own flag. No
//       __syncthreads in the loop.
// Safety (per plane w): flag_{w,s} >= k certifies wave w of block s published
//   h^k (vmcnt(0) drain precedes flag store) AND consumed slot (k-1)&1.
//   Step 0 consumes zero-registers, so hg needs no zero-init.
__global__ __launch_bounds__(256) void lstm_rec11_kernel(
        const _Float16* __restrict__ xz_f, const _Float16* __restrict__ xz_b,
        const u16* __restrict__ Ut_f, const u16* __restrict__ Ut_b,
        const int* __restrict__ mask,
        u32* __restrict__ flags,    // [dir*128 + wave*32 + slice] monotone counters
        u16* __restrict__ hg,       // [slot][dir][64][512] bf16, slot stride 65536
        u16* __restrict__ y_bf,     // layer1 out (null for layer2)
        float* __restrict__ y_f32,  // layer2 H out (null for layer1)
        float* __restrict__ hc_out) // layer2 hidden @0, cell @65536 (null for layer1)
{
    const int T = 256;
    int slice = blockIdx.x, dir = blockIdx.y;
    int tid = threadIdx.x;
    int lane = tid & 63, q = lane >> 4, col = lane & 15;
    int wv = tid >> 6;
    int ds = slice * 16, m0 = wv * 16;

    const _Float16* xz = dir ? xz_b : xz_f;
    const u16* Ut = dir ? Ut_b : Ut_f;
    u32* planeflags = flags + dir * 128 + wv * 32;   // this plane's 32 flags
    u32* myflag = planeflags + slice;

    // ---- stage U-slice into LDS once, per-fragment contiguous ----
    // cell = (g*16+kc)*64 + l; holds U[g*512+ds+(l&15)][kc*32+(l>>4)*8 ..+8].
    alignas(16) __shared__ u16 Ulds[4 * 16 * 64 * 8];  // 64 KB
    for (int cell = tid; cell < 4096; cell += 256) {
        int l = cell & 63, fr = cell >> 6;
        int kc = fr & 15, g = fr >> 4;
        *(uint4*)&Ulds[cell * 8] =
            *(const uint4*)(Ut + (size_t)(g * 512 + ds + (l & 15)) * 512 + kc * 32 + (l >> 4) * 8);
    }

    float creg[4] = {0.f, 0.f, 0.f, 0.f};
    float hreg[4] = {0.f, 0.f, 0.f, 0.f};
    __syncthreads();   // Ulds cross-wave staging only; no barriers inside the loop

    for (int it = 0; it < T; ++it) {
        int t = dir ? (T - 1 - it) : it;
        const u16* hsrc = hg + (it & 1) * 65536 + dir * 32768;
        u16* hdst = hg + ((it & 1) ^ 1) * 65536 + dir * 32768;

        // xz + mask loads for this step (independent of h) — issued before the poll
        f16x4 xzv[4];
        {
            const _Float16* xzt = xz + (((size_t)t * 32 + slice) * 64) * 64;
            #pragma unroll
            for (int r = 0; r < 4; ++r)
                xzv[r] = *(const f16x4*)(xzt + ((m0 + q * 4 + r) * 16 + col) * 4);
        }
        int mk[4];
        #pragma unroll
        for (int r = 0; r < 4; ++r) mk[r] = mask[(m0 + q * 4 + r) * T + t];

        // ---- poll this plane's 32 producer flags, then load h^{it} a-fragments ----
        bf16x8 afr[16];
        if (it == 0) {
            #pragma unroll
            for (int c = 0; c < 16; ++c)
                afr[c] = (bf16x8){0, 0, 0, 0, 0, 0, 0, 0};
        } else {
            u32 tgt = (u32)it;
            for (;;) {
                u32 f = __hip_atomic_load(planeflags + (lane & 31), __ATOMIC_RELAXED,
                                          __HIP_MEMORY_SCOPE_AGENT);
                if (__all(f >= tgt)) break;
                __builtin_amdgcn_s_sleep(1);
            }
            __builtin_amdgcn_sched_barrier(0);  // pin h loads after the poll
            const u64* hp = (const u64*)(hsrc + (size_t)(m0 + col) * 512 + q * 8);
            #pragma unroll
            for (int c = 0; c < 16; ++c) {
                union { u64 qw[2]; bf16x8 v; } u;
                u.qw[0] = __hip_atomic_load(hp + c * 8, __ATOMIC_RELAXED,
                                            __HIP_MEMORY_SCOPE_AGENT);
                u.qw[1] = __hip_atomic_load(hp + c * 8 + 1, __ATOMIC_RELAXED,
                                            __HIP_MEMORY_SCOPE_AGENT);
                afr[c] = u.v;
            }
        }

        // ---- z = h @ U for 4 gates x 16 dims x wave's 16 rows ----
        f32x4 acc[4];
        #pragma unroll
        for (int g = 0; g < 4; ++g) acc[g] = (f32x4){0.f, 0.f, 0.f, 0.f};
        #pragma unroll
        for (int kc = 0; kc < 16; ++kc) {
            #pragma unroll
            for (int g = 0; g < 4; ++g) {
                bf16x8 b = *(const bf16x8*)&Ulds[((g * 16 + kc) * 64 + lane) * 8];
                acc[g] = MFMA16(afr[kc], b, acc[g]);
            }
        }

        // ---- gates, state update ----
        u32 hbv[4];
        #pragma unroll
        for (int r = 0; r < 4; ++r) {
            float zi = acc[0][r] + (float)xzv[r][0];
            float zf = acc[1][r] + (float)xzv[r][1];
            float zg = acc[2][r] + (float)xzv[r][2];
            float zo = acc[3][r] + (float)xzv[r][3];
            float ig = sigmoidf_(zi);
            float fg = sigmoidf_(zf);
            float gg = tanhf_(zg);
            float og = sigmoidf_(zo);
            float cn = fg * creg[r] + ig * gg;
            float hn = og * tanhf_(cn);
            if (mk[r]) { creg[r] = cn; hreg[r] = hn; }
            hbv[r] = (u32)f2bf(hreg[r]);
        }

        // ---- publish h^{it+1}: pack dim pairs via shfl, WT u32 agent stores,
        //      per-wave drain, per-wave flag. Then y stores OFF the critical path.
        if (it < T - 1) {
            u32 part[4];
            #pragma unroll
            for (int r = 0; r < 4; ++r) part[r] = (u32)__shfl_xor((int)hbv[r], 1);
            int odd = col & 1;
            u32 p0 = odd ? (part[2] | (hbv[2] << 16)) : (hbv[0] | (part[0] << 16));
            u32 p1 = odd ? (part[3] | (hbv[3] << 16)) : (hbv[1] | (part[1] << 16));
            int r0 = q * 4 + (odd ? 2 : 0);
            u32* w0 = (u32*)(hdst + (size_t)(m0 + r0) * 512 + ds + (col & ~1));
            u32* w1 = (u32*)(hdst + (size_t)(m0 + r0 + 1) * 512 + ds + (col & ~1));
            __hip_atomic_store(w0, p0, __ATOMIC_RELAXED, __HIP_MEMORY_SCOPE_AGENT);
            __hip_atomic_store(w1, p1, __ATOMIC_RELAXED, __HIP_MEMORY_SCOPE_AGENT);
            // drain THIS WAVE's 2 WT stores (plus long-retired prev y stores)
            asm volatile("s_waitcnt vmcnt(0)" ::: "memory");
            if (lane == 0)
                __hip_atomic_store(myflag, (u32)(it + 1), __ATOMIC_RELAXED,
                                   __HIP_MEMORY_SCOPE_AGENT);
        }

        // ---- y stores after the publish (retire during next step's poll/compute) ----
        #pragma unroll
        for (int r = 0; r < 4; ++r) {
            int b = m0 + q * 4 + r;
            size_t ybase = ((size_t)b * T + t) * 1024 + dir * 512 + ds + col;
            if (y_bf) __builtin_nontemporal_store((u16)hbv[r], y_bf + ybase);
            else      __builtin_nontemporal_store(hreg[r], y_f32 + ybase);
        }
    }

    if (hc_out) {
        #pragma unroll
        for (int r = 0; r < 4; ++r) {
            int b = m0 + q * 4 + r;
            hc_out[(size_t)b * 1024 + dir * 512 + ds + col] = hreg[r];
            hc_out[65536 + (size_t)b * 1024 + dir * 512 + ds + col] = creg[r];
        }
    }
}

extern "C" void kernel_launch(void* const* d_in, const int* in_sizes, int n_in,
                              void* d_out, int out_size, void* d_ws, size_t ws_size,
                              hipStream_t stream) {
    const float* X   = (const float*)d_in[0];
    const float* Wf1 = (const float*)d_in[1];
    const float* Uf1 = (const float*)d_in[2];
    const float* bf1 = (const float*)d_in[3];
    const float* Wb1 = (const float*)d_in[4];
    const float* Ub1 = (const float*)d_in[5];
    const float* bb1 = (const float*)d_in[6];
    const float* Wf2 = (const float*)d_in[7];
    const float* Uf2 = (const float*)d_in[8];
    const float* bf2 = (const float*)d_in[9];
    const float* Wb2 = (const float*)d_in[10];
    const float* Ub2 = (const float*)d_in[11];
    const float* bb2 = (const float*)d_in[12];
    float* out = (float*)d_out;

    // scratch carved from d_out's H region (67.1 MB, dead until layer-2 rec):
    // y1bf 33.55 MB @0, Xbf 16.78 MB after; both consumed by layer-2 GEMMs (stream order).
    u16* y1bf = (u16*)d_out;
    u16* Xbf  = (u16*)((char*)d_out + 33554432);

    char* ws = (char*)d_ws;
    size_t off = 0;
    auto alloc = [&](size_t bytes) { char* p = ws + off; off = (off + bytes + 255) & ~(size_t)255; return p; };
    u16*  Wt1f  = (u16*)alloc(2048ull * 512 * 2);
    u16*  Wt1b  = (u16*)alloc(2048ull * 512 * 2);
    u16*  Wt2f  = (u16*)alloc(2048ull * 1024 * 2);
    u16*  Wt2b  = (u16*)alloc(2048ull * 1024 * 2);
    u16*  Ut1f  = (u16*)alloc(2048ull * 512 * 2);
    u16*  Ut1b  = (u16*)alloc(2048ull * 512 * 2);
    u16*  Ut2f  = (u16*)alloc(2048ull * 512 * 2);
    u16*  Ut2b  = (u16*)alloc(2048ull * 512 * 2);
    int*  maskb = (int*)alloc(16384ull * 4);
    // per-wave flags: 2 dirs x 4 waves x 32 slices = 256 u32 (1 KB)
    u32*  flags = (u32*)alloc(1024);
    // h exchange: 2 slots x 2 dirs x 64 x 512 bf16 = 256 KB (never read before
    // write: step 0 consumes zero registers, so no zero-init needed)
    u16*  hg    = (u16*)alloc(2ull * 2 * 64 * 512 * 2);
    _Float16* xzf = (_Float16*)alloc(16384ull * 2048 * 2);
    _Float16* xzb = (_Float16*)alloc(16384ull * 2048 * 2);
    (void)ws_size; (void)in_sizes; (void)n_in; (void)out_size;
    const int initN = 256;  // flag words only

    // prep
    mask_kernel<<<dim3(16384), dim3(64), 0, stream>>>(X, maskb);
    cast_bf16_kernel<<<dim3(8192), dim3(256), 0, stream>>>(X, Xbf, 16384 * 512);
    transpose_cast_kernel<<<dim3(64, 16), dim3(32, 8), 0, stream>>>(Wf1, Wt1f, 512, 2048);
    transpose_cast_kernel<<<dim3(64, 16), dim3(32, 8), 0, stream>>>(Wb1, Wt1b, 512, 2048);
    transpose_cast_kernel<<<dim3(64, 32), dim3(32, 8), 0, stream>>>(Wf2, Wt2f, 1024, 2048);
    transpose_cast_kernel<<<dim3(64, 32), dim3(32, 8), 0, stream>>>(Wb2, Wt2b, 1024, 2048);
    transpose_cast_kernel<<<dim3(64, 16), dim3(32, 8), 0, stream>>>(Uf1, Ut1f, 512, 2048);
    transpose_cast_kernel<<<dim3(64, 16), dim3(32, 8), 0, stream>>>(Ub1, Ut1b, 512, 2048);
    transpose_cast_kernel<<<dim3(64, 16), dim3(32, 8), 0, stream>>>(Uf2, Ut2f, 512, 2048);
    transpose_cast_kernel<<<dim3(64, 16), dim3(32, 8), 0, stream>>>(Ub2, Ut2b, 512, 2048);

    // layer 1
    gemm_xz_kernel<<<dim3(256, 32), dim3(256), 0, stream>>>(Xbf, Wt1f, bf1, xzf, 512);
    gemm_xz_kernel<<<dim3(256, 32), dim3(256), 0, stream>>>(Xbf, Wt1b, bb1, xzb, 512);
    init_rec_kernel<<<dim3(1), dim3(256), 0, stream>>>(flags, initN);
    lstm_rec11_kernel<<<dim3(32, 2), dim3(256), 0, stream>>>(
        xzf, xzb, Ut1f, Ut1b, maskb, flags, hg, y1bf, nullptr, nullptr);

    // layer 2
    gemm_xz_kernel<<<dim3(256, 32), dim3(256), 0, stream>>>(y1bf, Wt2f, bf2, xzf, 1024);
    gemm_xz_kernel<<<dim3(256, 32), dim3(256), 0, stream>>>(y1bf, Wt2b, bb2, xzb, 1024);
    init_rec_kernel<<<dim3(1), dim3(256), 0, stream>>>(flags, initN);
    lstm_rec11_kernel<<<dim3(32, 2), dim3(256), 0, stream>>>(
        xzf, xzb, Ut2f, Ut2b, maskb, flags, hg, nullptr, out, out + 16777216);
}

// Round 6
// 3875.106 us; speedup vs baseline: 1.5734x; 1.2382x over previous
//
#include <hip/hip_runtime.h>

typedef unsigned short u16;
typedef unsigned int u32;
typedef unsigned long long u64;
typedef __attribute__((ext_vector_type(8))) short bf16x8;
typedef __attribute__((ext_vector_type(4))) float f32x4;
typedef __attribute__((ext_vector_type(4))) _Float16 f16x4;

#define MFMA16(a, b, c) __builtin_amdgcn_mfma_f32_16x16x32_bf16((a), (b), (c), 0, 0, 0)

__device__ __forceinline__ u16 f2bf(float f) {
    union { float f; u32 u; } v; v.f = f;
    u32 r = v.u + 0x7FFFu + ((v.u >> 16) & 1u);
    return (u16)(r >> 16);
}
__device__ __forceinline__ float sigmoidf_(float x) {
    return 1.0f / (1.0f + __expf(-x));
}
__device__ __forceinline__ float tanhf_(float x) {
    float e = __expf(-2.0f * x);
    return (1.0f - e) / (1.0f + e);
}

// ---------------- mask: mask[row] = any(X[row, :512] != 0) ----------------
__global__ void mask_kernel(const float* __restrict__ X, int* __restrict__ mask) {
    int row = blockIdx.x;
    int lane = threadIdx.x;
    const float* r = X + (size_t)row * 512;
    int nz = 0;
    #pragma unroll
    for (int i = 0; i < 8; ++i) nz |= (r[lane + 64 * i] != 0.0f);
    nz = __any(nz);
    if (lane == 0) mask[row] = nz ? 1 : 0;
}

// ---------------- cast fp32 -> bf16 (4 elems/thread) ----------------
__global__ void cast_bf16_kernel(const float* __restrict__ in, u16* __restrict__ out, int n) {
    int i = (blockIdx.x * blockDim.x + threadIdx.x) * 4;
    if (i + 3 < n) {
        float4 v = *(const float4*)(in + i);
        u32 a = (u32)f2bf(v.x) | ((u32)f2bf(v.y) << 16);
        u32 b = (u32)f2bf(v.z) | ((u32)f2bf(v.w) << 16);
        *(uint2*)(out + i) = make_uint2(a, b);
    }
}

// ---------------- transpose + cast: in fp32 [K][N] -> out bf16 [N][K] ----------------
__global__ void transpose_cast_kernel(const float* __restrict__ in, u16* __restrict__ out,
                                      int K, int N) {
    __shared__ float tile[32][33];
    int k0 = blockIdx.y * 32, n0 = blockIdx.x * 32;
    int tx = threadIdx.x, ty = threadIdx.y;
    #pragma unroll
    for (int i = ty; i < 32; i += 8)
        tile[i][tx] = in[(size_t)(k0 + i) * N + (n0 + tx)];
    __syncthreads();
    #pragma unroll
    for (int i = ty; i < 32; i += 8)
        out[(size_t)(n0 + i) * K + (k0 + tx)] = f2bf(tile[tx][i]);
}

// ---------------- GEMM: xz = A @ Bt^T + bias, gate-fused n-tiling ----------
// R15: 4 m-fragments per wave (R14 had 1). Per K-chunk: 4 A-loads + 4 B-loads
// feed 16 independent MFMAs (2:1 MFMA:VMEM, was 4:5) -- the loop was
// load/address-issue-bound at ~150 TF. Block covers 256 rows x one dim-slice
// x all 4 gates; B rows shared by all 4 waves (L1-served). Epilogue unchanged
// from R14: each lane packs 4 gate values -> ONE u64 store per row.
// C element index unchanged: (((t*32 + slice)*64 + b)*16 + dcol)*4 + g.
__global__ __launch_bounds__(256) void gemm_xz_kernel(
        const u16* __restrict__ A, const u16* __restrict__ Bt,
        const float* __restrict__ bias, _Float16* __restrict__ C, int K) {
    int w = threadIdx.x >> 6, lane = threadIdx.x & 63;
    int q = lane >> 4, col = lane & 15;
    int m0 = blockIdx.x * 256 + w * 64;   // wave's 64 rows (4 m-frags of 16)
    int sl = blockIdx.y;                  // dim-slice 0..31

    const u16* arow = A + (size_t)(m0 + col) * K + q * 8;   // mf adds mf*16*K
    const u16* brow = Bt + (size_t)(sl * 16 + col) * K + q * 8;  // g adds g*512*K

    f32x4 acc[4][4];   // [mf][g]
    #pragma unroll
    for (int mf = 0; mf < 4; ++mf)
        #pragma unroll
        for (int g = 0; g < 4; ++g) acc[mf][g] = (f32x4){0.f, 0.f, 0.f, 0.f};

    #pragma unroll 2
    for (int kc = 0; kc < K; kc += 32) {
        bf16x8 b[4], a[4];
        #pragma unroll
        for (int g = 0; g < 4; ++g)
            b[g] = *(const bf16x8*)(brow + (size_t)g * 512 * K + kc);
        #pragma unroll
        for (int mf = 0; mf < 4; ++mf)
            a[mf] = *(const bf16x8*)(arow + (size_t)mf * 16 * K + kc);
        #pragma unroll
        for (int mf = 0; mf < 4; ++mf)
            #pragma unroll
            for (int g = 0; g < 4; ++g)
                acc[mf][g] = MFMA16(a[mf], b[g], acc[mf][g]);
    }

    float bs[4];
    #pragma unroll
    for (int g = 0; g < 4; ++g) bs[g] = bias[g * 512 + sl * 16 + col];

    #pragma unroll
    for (int mf = 0; mf < 4; ++mf) {
        #pragma unroll
        for (int r = 0; r < 4; ++r) {
            int row = m0 + mf * 16 + q * 4 + r;
            int b = row >> 8, t = row & 255;
            union { _Float16 h[4]; u64 u; } pk;
            #pragma unroll
            for (int g = 0; g < 4; ++g) pk.h[g] = (_Float16)(acc[mf][g][r] + bs[g]);
            size_t uidx = (((size_t)t * 32 + sl) * 64 + b) * 16 + col;
            ((u64*)C)[uidx] = pk.u;
        }
    }
}

// ---------------- zero-init (flags) ----------------
__global__ void init_rec_kernel(u32* __restrict__ p, int n) {
    int i = blockIdx.x * 256 + threadIdx.x;
    if (i < n) p[i] = 0;
}

// ---------------- persistent d-sliced LSTM recurrence, v11: per-wave flags ---------
// (verbatim: round-3/5 kernel, 1535 us/dispatch; protocol frozen — rec9/10/12
//  variants all regressed.)
// grid (32 slices, 2 dirs) x 256 thr (4 waves). Block owns 16 h-dims x 4 gates.
//   (a) y stores after the flag publish; their HBM ACK drains during the next
//       step's poll wait, which is concurrent with waiting for producers.
//   (b) per-WAVE flags: exchange partitioned into 4 row-planes (producer wave w
//       writes rows 16w..16w+15; consumer wave w reads exactly those rows), so
//       each wave drains its own 2 WT stores and fires its own flag. No
//       __syncthreads in the loop.
// Safety (per plane w): flag_{w,s} >= k certifies wave w of block s published
//   h^k (vmcnt(0) drain precedes flag store) AND consumed slot (k-1)&1.
//   Step 0 consumes zero-registers, so hg needs no zero-init.
__global__ __launch_bounds__(256) void lstm_rec11_kernel(
        const _Float16* __restrict__ xz_f, const _Float16* __restrict__ xz_b,
        const u16* __restrict__ Ut_f, const u16* __restrict__ Ut_b,
        const int* __restrict__ mask,
        u32* __restrict__ flags,    // [dir*128 + wave*32 + slice] monotone counters
        u16* __restrict__ hg,       // [slot][dir][64][512] bf16, slot stride 65536
        u16* __restrict__ y_bf,     // layer1 out (null for layer2)
        float* __restrict__ y_f32,  // layer2 H out (null for layer1)
        float* __restrict__ hc_out) // layer2 hidden @0, cell @65536 (null for layer1)
{
    const int T = 256;
    int slice = blockIdx.x, dir = blockIdx.y;
    int tid = threadIdx.x;
    int lane = tid & 63, q = lane >> 4, col = lane & 15;
    int wv = tid >> 6;
    int ds = slice * 16, m0 = wv * 16;

    const _Float16* xz = dir ? xz_b : xz_f;
    const u16* Ut = dir ? Ut_b : Ut_f;
    u32* planeflags = flags + dir * 128 + wv * 32;   // this plane's 32 flags
    u32* myflag = planeflags + slice;

    // ---- stage U-slice into LDS once, per-fragment contiguous ----
    // cell = (g*16+kc)*64 + l; holds U[g*512+ds+(l&15)][kc*32+(l>>4)*8 ..+8].
    alignas(16) __shared__ u16 Ulds[4 * 16 * 64 * 8];  // 64 KB
    for (int cell = tid; cell < 4096; cell += 256) {
        int l = cell & 63, fr = cell >> 6;
        int kc = fr & 15, g = fr >> 4;
        *(uint4*)&Ulds[cell * 8] =
            *(const uint4*)(Ut + (size_t)(g * 512 + ds + (l & 15)) * 512 + kc * 32 + (l >> 4) * 8);
    }

    float creg[4] = {0.f, 0.f, 0.f, 0.f};
    float hreg[4] = {0.f, 0.f, 0.f, 0.f};
    __syncthreads();   // Ulds cross-wave staging only; no barriers inside the loop

    for (int it = 0; it < T; ++it) {
        int t = dir ? (T - 1 - it) : it;
        const u16* hsrc = hg + (it & 1) * 65536 + dir * 32768;
        u16* hdst = hg + ((it & 1) ^ 1) * 65536 + dir * 32768;

        // xz + mask loads for this step (independent of h) — issued before the poll
        f16x4 xzv[4];
        {
            const _Float16* xzt = xz + (((size_t)t * 32 + slice) * 64) * 64;
            #pragma unroll
            for (int r = 0; r < 4; ++r)
                xzv[r] = *(const f16x4*)(xzt + ((m0 + q * 4 + r) * 16 + col) * 4);
        }
        int mk[4];
        #pragma unroll
        for (int r = 0; r < 4; ++r) mk[r] = mask[(m0 + q * 4 + r) * T + t];

        // ---- poll this plane's 32 producer flags, then load h^{it} a-fragments ----
        bf16x8 afr[16];
        if (it == 0) {
            #pragma unroll
            for (int c = 0; c < 16; ++c)
                afr[c] = (bf16x8){0, 0, 0, 0, 0, 0, 0, 0};
        } else {
            u32 tgt = (u32)it;
            for (;;) {
                u32 f = __hip_atomic_load(planeflags + (lane & 31), __ATOMIC_RELAXED,
                                          __HIP_MEMORY_SCOPE_AGENT);
                if (__all(f >= tgt)) break;
                __builtin_amdgcn_s_sleep(1);
            }
            __builtin_amdgcn_sched_barrier(0);  // pin h loads after the poll
            const u64* hp = (const u64*)(hsrc + (size_t)(m0 + col) * 512 + q * 8);
            #pragma unroll
            for (int c = 0; c < 16; ++c) {
                union { u64 qw[2]; bf16x8 v; } u;
                u.qw[0] = __hip_atomic_load(hp + c * 8, __ATOMIC_RELAXED,
                                            __HIP_MEMORY_SCOPE_AGENT);
                u.qw[1] = __hip_atomic_load(hp + c * 8 + 1, __ATOMIC_RELAXED,
                                            __HIP_MEMORY_SCOPE_AGENT);
                afr[c] = u.v;
            }
        }

        // ---- z = h @ U for 4 gates x 16 dims x wave's 16 rows ----
        f32x4 acc[4];
        #pragma unroll
        for (int g = 0; g < 4; ++g) acc[g] = (f32x4){0.f, 0.f, 0.f, 0.f};
        #pragma unroll
        for (int kc = 0; kc < 16; ++kc) {
            #pragma unroll
            for (int g = 0; g < 4; ++g) {
                bf16x8 b = *(const bf16x8*)&Ulds[((g * 16 + kc) * 64 + lane) * 8];
                acc[g] = MFMA16(afr[kc], b, acc[g]);
            }
        }

        // ---- gates, state update ----
        u32 hbv[4];
        #pragma unroll
        for (int r = 0; r < 4; ++r) {
            float zi = acc[0][r] + (float)xzv[r][0];
            float zf = acc[1][r] + (float)xzv[r][1];
            float zg = acc[2][r] + (float)xzv[r][2];
            float zo = acc[3][r] + (float)xzv[r][3];
            float ig = sigmoidf_(zi);
            float fg = sigmoidf_(zf);
            float gg = tanhf_(zg);
            float og = sigmoidf_(zo);
            float cn = fg * creg[r] + ig * gg;
            float hn = og * tanhf_(cn);
            if (mk[r]) { creg[r] = cn; hreg[r] = hn; }
            hbv[r] = (u32)f2bf(hreg[r]);
        }

        // ---- publish h^{it+1}: pack dim pairs via shfl, WT u32 agent stores,
        //      per-wave drain, per-wave flag. Then y stores OFF the critical path.
        if (it < T - 1) {
            u32 part[4];
            #pragma unroll
            for (int r = 0; r < 4; ++r) part[r] = (u32)__shfl_xor((int)hbv[r], 1);
            int odd = col & 1;
            u32 p0 = odd ? (part[2] | (hbv[2] << 16)) : (hbv[0] | (part[0] << 16));
            u32 p1 = odd ? (part[3] | (hbv[3] << 16)) : (hbv[1] | (part[1] << 16));
            int r0 = q * 4 + (odd ? 2 : 0);
            u32* w0 = (u32*)(hdst + (size_t)(m0 + r0) * 512 + ds + (col & ~1));
            u32* w1 = (u32*)(hdst + (size_t)(m0 + r0 + 1) * 512 + ds + (col & ~1));
            __hip_atomic_store(w0, p0, __ATOMIC_RELAXED, __HIP_MEMORY_SCOPE_AGENT);
            __hip_atomic_store(w1, p1, __ATOMIC_RELAXED, __HIP_MEMORY_SCOPE_AGENT);
            // drain THIS WAVE's 2 WT stores (plus long-retired prev y stores)
            asm volatile("s_waitcnt vmcnt(0)" ::: "memory");
            if (lane == 0)
                __hip_atomic_store(myflag, (u32)(it + 1), __ATOMIC_RELAXED,
                                   __HIP_MEMORY_SCOPE_AGENT);
        }

        // ---- y stores after the publish (retire during next step's poll/compute) ----
        #pragma unroll
        for (int r = 0; r < 4; ++r) {
            int b = m0 + q * 4 + r;
            size_t ybase = ((size_t)b * T + t) * 1024 + dir * 512 + ds + col;
            if (y_bf) __builtin_nontemporal_store((u16)hbv[r], y_bf + ybase);
            else      __builtin_nontemporal_store(hreg[r], y_f32 + ybase);
        }
    }

    if (hc_out) {
        #pragma unroll
        for (int r = 0; r < 4; ++r) {
            int b = m0 + q * 4 + r;
            hc_out[(size_t)b * 1024 + dir * 512 + ds + col] = hreg[r];
            hc_out[65536 + (size_t)b * 1024 + dir * 512 + ds + col] = creg[r];
        }
    }
}

extern "C" void kernel_launch(void* const* d_in, const int* in_sizes, int n_in,
                              void* d_out, int out_size, void* d_ws, size_t ws_size,
                              hipStream_t stream) {
    const float* X   = (const float*)d_in[0];
    const float* Wf1 = (const float*)d_in[1];
    const float* Uf1 = (const float*)d_in[2];
    const float* bf1 = (const float*)d_in[3];
    const float* Wb1 = (const float*)d_in[4];
    const float* Ub1 = (const float*)d_in[5];
    const float* bb1 = (const float*)d_in[6];
    const float* Wf2 = (const float*)d_in[7];
    const float* Uf2 = (const float*)d_in[8];
    const float* bf2 = (const float*)d_in[9];
    const float* Wb2 = (const float*)d_in[10];
    const float* Ub2 = (const float*)d_in[11];
    const float* bb2 = (const float*)d_in[12];
    float* out = (float*)d_out;

    // scratch carved from d_out's H region (67.1 MB, dead until layer-2 rec):
    // y1bf 33.55 MB @0, Xbf 16.78 MB after; both consumed by layer-2 GEMMs (stream order).
    u16* y1bf = (u16*)d_out;
    u16* Xbf  = (u16*)((char*)d_out + 33554432);

    char* ws = (char*)d_ws;
    size_t off = 0;
    auto alloc = [&](size_t bytes) { char* p = ws + off; off = (off + bytes + 255) & ~(size_t)255; return p; };
    u16*  Wt1f  = (u16*)alloc(2048ull * 512 * 2);
    u16*  Wt1b  = (u16*)alloc(2048ull * 512 * 2);
    u16*  Wt2f  = (u16*)alloc(2048ull * 1024 * 2);
    u16*  Wt2b  = (u16*)alloc(2048ull * 1024 * 2);
    u16*  Ut1f  = (u16*)alloc(2048ull * 512 * 2);
    u16*  Ut1b  = (u16*)alloc(2048ull * 512 * 2);
    u16*  Ut2f  = (u16*)alloc(2048ull * 512 * 2);
    u16*  Ut2b  = (u16*)alloc(2048ull * 512 * 2);
    int*  maskb = (int*)alloc(16384ull * 4);
    // per-wave flags: 2 dirs x 4 waves x 32 slices = 256 u32 (1 KB)
    u32*  flags = (u32*)alloc(1024);
    // h exchange: 2 slots x 2 dirs x 64 x 512 bf16 = 256 KB (never read before
    // write: step 0 consumes zero registers, so no zero-init needed)
    u16*  hg    = (u16*)alloc(2ull * 2 * 64 * 512 * 2);
    _Float16* xzf = (_Float16*)alloc(16384ull * 2048 * 2);
    _Float16* xzb = (_Float16*)alloc(16384ull * 2048 * 2);
    (void)ws_size; (void)in_sizes; (void)n_in; (void)out_size;
    const int initN = 256;  // flag words only

    // prep
    mask_kernel<<<dim3(16384), dim3(64), 0, stream>>>(X, maskb);
    cast_bf16_kernel<<<dim3(8192), dim3(256), 0, stream>>>(X, Xbf, 16384 * 512);
    transpose_cast_kernel<<<dim3(64, 16), dim3(32, 8), 0, stream>>>(Wf1, Wt1f, 512, 2048);
    transpose_cast_kernel<<<dim3(64, 16), dim3(32, 8), 0, stream>>>(Wb1, Wt1b, 512, 2048);
    transpose_cast_kernel<<<dim3(64, 32), dim3(32, 8), 0, stream>>>(Wf2, Wt2f, 1024, 2048);
    transpose_cast_kernel<<<dim3(64, 32), dim3(32, 8), 0, stream>>>(Wb2, Wt2b, 1024, 2048);
    transpose_cast_kernel<<<dim3(64, 16), dim3(32, 8), 0, stream>>>(Uf1, Ut1f, 512, 2048);
    transpose_cast_kernel<<<dim3(64, 16), dim3(32, 8), 0, stream>>>(Ub1, Ut1b, 512, 2048);
    transpose_cast_kernel<<<dim3(64, 16), dim3(32, 8), 0, stream>>>(Uf2, Ut2f, 512, 2048);
    transpose_cast_kernel<<<dim3(64, 16), dim3(32, 8), 0, stream>>>(Ub2, Ut2b, 512, 2048);

    // layer 1
    gemm_xz_kernel<<<dim3(64, 32), dim3(256), 0, stream>>>(Xbf, Wt1f, bf1, xzf, 512);
    gemm_xz_kernel<<<dim3(64, 32), dim3(256), 0, stream>>>(Xbf, Wt1b, bb1, xzb, 512);
    init_rec_kernel<<<dim3(1), dim3(256), 0, stream>>>(flags, initN);
    lstm_rec11_kernel<<<dim3(32, 2), dim3(256), 0, stream>>>(
        xzf, xzb, Ut1f, Ut1b, maskb, flags, hg, y1bf, nullptr, nullptr);

    // layer 2
    gemm_xz_kernel<<<dim3(64, 32), dim3(256), 0, stream>>>(y1bf, Wt2f, bf2, xzf, 1024);
    gemm_xz_kernel<<<dim3(64, 32), dim3(256), 0, stream>>>(y1bf, Wt2b, bb2, xzb, 1024);
    init_rec_kernel<<<dim3(1), dim3(256), 0, stream>>>(flags, initN);
    lstm_rec11_kernel<<<dim3(32, 2), dim3(256), 0, stream>>>(
        xzf, xzb, Ut2f, Ut2b, maskb, flags, hg, nullptr, out, out + 16777216);
}

// Round 7
// 3811.585 us; speedup vs baseline: 1.5996x; 1.0167x over previous
//
#include <hip/hip_runtime.h>

typedef unsigned short u16;
typedef unsigned int u32;
typedef unsigned long long u64;
typedef __attribute__((ext_vector_type(8))) short bf16x8;
typedef __attribute__((ext_vector_type(4))) float f32x4;
typedef __attribute__((ext_vector_type(4))) _Float16 f16x4;

#define MFMA16(a, b, c) __builtin_amdgcn_mfma_f32_16x16x32_bf16((a), (b), (c), 0, 0, 0)

__device__ __forceinline__ u16 f2bf(float f) {
    union { float f; u32 u; } v; v.f = f;
    u32 r = v.u + 0x7FFFu + ((v.u >> 16) & 1u);
    return (u16)(r >> 16);
}
__device__ __forceinline__ float sigmoidf_(float x) {
    return 1.0f / (1.0f + __expf(-x));
}
__device__ __forceinline__ float tanhf_(float x) {
    float e = __expf(-2.0f * x);
    return (1.0f - e) / (1.0f + e);
}

// ---------------- mask: mask[row] = any(X[row, :512] != 0) ----------------
__global__ void mask_kernel(const float* __restrict__ X, int* __restrict__ mask) {
    int row = blockIdx.x;
    int lane = threadIdx.x;
    const float* r = X + (size_t)row * 512;
    int nz = 0;
    #pragma unroll
    for (int i = 0; i < 8; ++i) nz |= (r[lane + 64 * i] != 0.0f);
    nz = __any(nz);
    if (lane == 0) mask[row] = nz ? 1 : 0;
}

// ---------------- cast fp32 -> bf16 (4 elems/thread) ----------------
__global__ void cast_bf16_kernel(const float* __restrict__ in, u16* __restrict__ out, int n) {
    int i = (blockIdx.x * blockDim.x + threadIdx.x) * 4;
    if (i + 3 < n) {
        float4 v = *(const float4*)(in + i);
        u32 a = (u32)f2bf(v.x) | ((u32)f2bf(v.y) << 16);
        u32 b = (u32)f2bf(v.z) | ((u32)f2bf(v.w) << 16);
        *(uint2*)(out + i) = make_uint2(a, b);
    }
}

// ---------------- transpose + cast: in fp32 [K][N] -> out bf16 [N][K] ----------------
__global__ void transpose_cast_kernel(const float* __restrict__ in, u16* __restrict__ out,
                                      int K, int N) {
    __shared__ float tile[32][33];
    int k0 = blockIdx.y * 32, n0 = blockIdx.x * 32;
    int tx = threadIdx.x, ty = threadIdx.y;
    #pragma unroll
    for (int i = ty; i < 32; i += 8)
        tile[i][tx] = in[(size_t)(k0 + i) * N + (n0 + tx)];
    __syncthreads();
    #pragma unroll
    for (int i = ty; i < 32; i += 8)
        out[(size_t)(n0 + i) * K + (k0 + tx)] = f2bf(tile[tx][i]);
}

// ---------------- GEMM: xz = A @ Bt^T + bias, gate-fused n-tiling ----------
// R16: 2 dim-slices per block (NF=8 n-frags = 2 dcol-halves x 4 gates),
// grid.y 32->16. A-rereads from LLC halve (layer-2: 1.07 GB -> 537 MB; A-traffic
// was the dominant GEMM term). Per wave: 4 m-frags x 8 n-frags = 32 MFMAs per
// 12 loads. Epilogue: R14's verified u64-contiguous store, one per (mf,r,half).
// C element index unchanged: (((t*32 + slice)*64 + b)*16 + dcol)*4 + g,
// where slice = sl*2 + half.
__global__ __launch_bounds__(256) void gemm_xz_kernel(
        const u16* __restrict__ A, const u16* __restrict__ Bt,
        const float* __restrict__ bias, _Float16* __restrict__ C, int K) {
    int w = threadIdx.x >> 6, lane = threadIdx.x & 63;
    int q = lane >> 4, col = lane & 15;
    int m0 = blockIdx.x * 256 + w * 64;   // wave's 64 rows (4 m-frags of 16)
    int sl = blockIdx.y;                  // double-slice 0..15 (dcols sl*32..+31)

    const u16* arow = A + (size_t)(m0 + col) * K + q * 8;        // + mf*16*K
    const u16* brow = Bt + (size_t)(sl * 32 + col) * K + q * 8;  // + (half*16+g*512)*K

    f32x4 acc[4][8];   // [mf][half*4+g]
    #pragma unroll
    for (int mf = 0; mf < 4; ++mf)
        #pragma unroll
        for (int j = 0; j < 8; ++j) acc[mf][j] = (f32x4){0.f, 0.f, 0.f, 0.f};

    #pragma unroll 1
    for (int kc = 0; kc < K; kc += 32) {
        bf16x8 b[8], a[4];
        #pragma unroll
        for (int j = 0; j < 8; ++j) {
            int g = j & 3, half = j >> 2;
            b[j] = *(const bf16x8*)(brow + (size_t)(g * 512 + half * 16) * K + kc);
        }
        #pragma unroll
        for (int mf = 0; mf < 4; ++mf)
            a[mf] = *(const bf16x8*)(arow + (size_t)mf * 16 * K + kc);
        #pragma unroll
        for (int mf = 0; mf < 4; ++mf)
            #pragma unroll
            for (int j = 0; j < 8; ++j)
                acc[mf][j] = MFMA16(a[mf], b[j], acc[mf][j]);
    }

    float bs[8];
    #pragma unroll
    for (int j = 0; j < 8; ++j) {
        int g = j & 3, half = j >> 2;
        bs[j] = bias[g * 512 + sl * 32 + half * 16 + col];
    }

    #pragma unroll
    for (int mf = 0; mf < 4; ++mf) {
        #pragma unroll
        for (int r = 0; r < 4; ++r) {
            int row = m0 + mf * 16 + q * 4 + r;
            int b = row >> 8, t = row & 255;
            #pragma unroll
            for (int half = 0; half < 2; ++half) {
                union { _Float16 h[4]; u64 u; } pk;
                #pragma unroll
                for (int g = 0; g < 4; ++g)
                    pk.h[g] = (_Float16)(acc[mf][half * 4 + g][r] + bs[half * 4 + g]);
                size_t uidx = (((size_t)t * 32 + (sl * 2 + half)) * 64 + b) * 16 + col;
                ((u64*)C)[uidx] = pk.u;
            }
        }
    }
}

// ---------------- zero-init (flags) ----------------
__global__ void init_rec_kernel(u32* __restrict__ p, int n) {
    int i = blockIdx.x * 256 + threadIdx.x;
    if (i < n) p[i] = 0;
}

// ---------------- persistent d-sliced LSTM recurrence, v11: per-wave flags ---------
// (verbatim: round-3/5/6 kernel, 1535 us/dispatch; protocol frozen — rec9/10/12
//  variants all regressed.)
// grid (32 slices, 2 dirs) x 256 thr (4 waves). Block owns 16 h-dims x 4 gates.
//   (a) y stores after the flag publish; their HBM ACK drains during the next
//       step's poll wait, which is concurrent with waiting for producers.
//   (b) per-WAVE flags: exchange partitioned into 4 row-planes (producer wave w
//       writes rows 16w..16w+15; consumer wave w reads exactly those rows), so
//       each wave drains its own 2 WT stores and fires its own flag. No
//       __syncthreads in the loop.
// Safety (per plane w): flag_{w,s} >= k certifies wave w of block s published
//   h^k (vmcnt(0) drain precedes flag store) AND consumed slot (k-1)&1.
//   Step 0 consumes zero-registers, so hg needs no zero-init.
__global__ __launch_bounds__(256) void lstm_rec11_kernel(
        const _Float16* __restrict__ xz_f, const _Float16* __restrict__ xz_b,
        const u16* __restrict__ Ut_f, const u16* __restrict__ Ut_b,
        const int* __restrict__ mask,
        u32* __restrict__ flags,    // [dir*128 + wave*32 + slice] monotone counters
        u16* __restrict__ hg,       // [slot][dir][64][512] bf16, slot stride 65536
        u16* __restrict__ y_bf,     // layer1 out (null for layer2)
        float* __restrict__ y_f32,  // layer2 H out (null for layer1)
        float* __restrict__ hc_out) // layer2 hidden @0, cell @65536 (null for layer1)
{
    const int T = 256;
    int slice = blockIdx.x, dir = blockIdx.y;
    int tid = threadIdx.x;
    int lane = tid & 63, q = lane >> 4, col = lane & 15;
    int wv = tid >> 6;
    int ds = slice * 16, m0 = wv * 16;

    const _Float16* xz = dir ? xz_b : xz_f;
    const u16* Ut = dir ? Ut_b : Ut_f;
    u32* planeflags = flags + dir * 128 + wv * 32;   // this plane's 32 flags
    u32* myflag = planeflags + slice;

    // ---- stage U-slice into LDS once, per-fragment contiguous ----
    // cell = (g*16+kc)*64 + l; holds U[g*512+ds+(l&15)][kc*32+(l>>4)*8 ..+8].
    alignas(16) __shared__ u16 Ulds[4 * 16 * 64 * 8];  // 64 KB
    for (int cell = tid; cell < 4096; cell += 256) {
        int l = cell & 63, fr = cell >> 6;
        int kc = fr & 15, g = fr >> 4;
        *(uint4*)&Ulds[cell * 8] =
            *(const uint4*)(Ut + (size_t)(g * 512 + ds + (l & 15)) * 512 + kc * 32 + (l >> 4) * 8);
    }

    float creg[4] = {0.f, 0.f, 0.f, 0.f};
    float hreg[4] = {0.f, 0.f, 0.f, 0.f};
    __syncthreads();   // Ulds cross-wave staging only; no barriers inside the loop

    for (int it = 0; it < T; ++it) {
        int t = dir ? (T - 1 - it) : it;
        const u16* hsrc = hg + (it & 1) * 65536 + dir * 32768;
        u16* hdst = hg + ((it & 1) ^ 1) * 65536 + dir * 32768;

        // xz + mask loads for this step (independent of h) — issued before the poll
        f16x4 xzv[4];
        {
            const _Float16* xzt = xz + (((size_t)t * 32 + slice) * 64) * 64;
            #pragma unroll
            for (int r = 0; r < 4; ++r)
                xzv[r] = *(const f16x4*)(xzt + ((m0 + q * 4 + r) * 16 + col) * 4);
        }
        int mk[4];
        #pragma unroll
        for (int r = 0; r < 4; ++r) mk[r] = mask[(m0 + q * 4 + r) * T + t];

        // ---- poll this plane's 32 producer flags, then load h^{it} a-fragments ----
        bf16x8 afr[16];
        if (it == 0) {
            #pragma unroll
            for (int c = 0; c < 16; ++c)
                afr[c] = (bf16x8){0, 0, 0, 0, 0, 0, 0, 0};
        } else {
            u32 tgt = (u32)it;
            for (;;) {
                u32 f = __hip_atomic_load(planeflags + (lane & 31), __ATOMIC_RELAXED,
                                          __HIP_MEMORY_SCOPE_AGENT);
                if (__all(f >= tgt)) break;
                __builtin_amdgcn_s_sleep(1);
            }
            __builtin_amdgcn_sched_barrier(0);  // pin h loads after the poll
            const u64* hp = (const u64*)(hsrc + (size_t)(m0 + col) * 512 + q * 8);
            #pragma unroll
            for (int c = 0; c < 16; ++c) {
                union { u64 qw[2]; bf16x8 v; } u;
                u.qw[0] = __hip_atomic_load(hp + c * 8, __ATOMIC_RELAXED,
                                            __HIP_MEMORY_SCOPE_AGENT);
                u.qw[1] = __hip_atomic_load(hp + c * 8 + 1, __ATOMIC_RELAXED,
                                            __HIP_MEMORY_SCOPE_AGENT);
                afr[c] = u.v;
            }
        }

        // ---- z = h @ U for 4 gates x 16 dims x wave's 16 rows ----
        f32x4 acc[4];
        #pragma unroll
        for (int g = 0; g < 4; ++g) acc[g] = (f32x4){0.f, 0.f, 0.f, 0.f};
        #pragma unroll
        for (int kc = 0; kc < 16; ++kc) {
            #pragma unroll
            for (int g = 0; g < 4; ++g) {
                bf16x8 b = *(const bf16x8*)&Ulds[((g * 16 + kc) * 64 + lane) * 8];
                acc[g] = MFMA16(afr[kc], b, acc[g]);
            }
        }

        // ---- gates, state update ----
        u32 hbv[4];
        #pragma unroll
        for (int r = 0; r < 4; ++r) {
            float zi = acc[0][r] + (float)xzv[r][0];
            float zf = acc[1][r] + (float)xzv[r][1];
            float zg = acc[2][r] + (float)xzv[r][2];
            float zo = acc[3][r] + (float)xzv[r][3];
            float ig = sigmoidf_(zi);
            float fg = sigmoidf_(zf);
            float gg = tanhf_(zg);
            float og = sigmoidf_(zo);
            float cn = fg * creg[r] + ig * gg;
            float hn = og * tanhf_(cn);
            if (mk[r]) { creg[r] = cn; hreg[r] = hn; }
            hbv[r] = (u32)f2bf(hreg[r]);
        }

        // ---- publish h^{it+1}: pack dim pairs via shfl, WT u32 agent stores,
        //      per-wave drain, per-wave flag. Then y stores OFF the critical path.
        if (it < T - 1) {
            u32 part[4];
            #pragma unroll
            for (int r = 0; r < 4; ++r) part[r] = (u32)__shfl_xor((int)hbv[r], 1);
            int odd = col & 1;
            u32 p0 = odd ? (part[2] | (hbv[2] << 16)) : (hbv[0] | (part[0] << 16));
            u32 p1 = odd ? (part[3] | (hbv[3] << 16)) : (hbv[1] | (part[1] << 16));
            int r0 = q * 4 + (odd ? 2 : 0);
            u32* w0 = (u32*)(hdst + (size_t)(m0 + r0) * 512 + ds + (col & ~1));
            u32* w1 = (u32*)(hdst + (size_t)(m0 + r0 + 1) * 512 + ds + (col & ~1));
            __hip_atomic_store(w0, p0, __ATOMIC_RELAXED, __HIP_MEMORY_SCOPE_AGENT);
            __hip_atomic_store(w1, p1, __ATOMIC_RELAXED, __HIP_MEMORY_SCOPE_AGENT);
            // drain THIS WAVE's 2 WT stores (plus long-retired prev y stores)
            asm volatile("s_waitcnt vmcnt(0)" ::: "memory");
            if (lane == 0)
                __hip_atomic_store(myflag, (u32)(it + 1), __ATOMIC_RELAXED,
                                   __HIP_MEMORY_SCOPE_AGENT);
        }

        // ---- y stores after the publish (retire during next step's poll/compute) ----
        #pragma unroll
        for (int r = 0; r < 4; ++r) {
            int b = m0 + q * 4 + r;
            size_t ybase = ((size_t)b * T + t) * 1024 + dir * 512 + ds + col;
            if (y_bf) __builtin_nontemporal_store((u16)hbv[r], y_bf + ybase);
            else      __builtin_nontemporal_store(hreg[r], y_f32 + ybase);
        }
    }

    if (hc_out) {
        #pragma unroll
        for (int r = 0; r < 4; ++r) {
            int b = m0 + q * 4 + r;
            hc_out[(size_t)b * 1024 + dir * 512 + ds + col] = hreg[r];
            hc_out[65536 + (size_t)b * 1024 + dir * 512 + ds + col] = creg[r];
        }
    }
}

extern "C" void kernel_launch(void* const* d_in, const int* in_sizes, int n_in,
                              void* d_out, int out_size, void* d_ws, size_t ws_size,
                              hipStream_t stream) {
    const float* X   = (const float*)d_in[0];
    const float* Wf1 = (const float*)d_in[1];
    const float* Uf1 = (const float*)d_in[2];
    const float* bf1 = (const float*)d_in[3];
    const float* Wb1 = (const float*)d_in[4];
    const float* Ub1 = (const float*)d_in[5];
    const float* bb1 = (const float*)d_in[6];
    const float* Wf2 = (const float*)d_in[7];
    const float* Uf2 = (const float*)d_in[8];
    const float* bf2 = (const float*)d_in[9];
    const float* Wb2 = (const float*)d_in[10];
    const float* Ub2 = (const float*)d_in[11];
    const float* bb2 = (const float*)d_in[12];
    float* out = (float*)d_out;

    // scratch carved from d_out's H region (67.1 MB, dead until layer-2 rec):
    // y1bf 33.55 MB @0, Xbf 16.78 MB after; both consumed by layer-2 GEMMs (stream order).
    u16* y1bf = (u16*)d_out;
    u16* Xbf  = (u16*)((char*)d_out + 33554432);

    char* ws = (char*)d_ws;
    size_t off = 0;
    auto alloc = [&](size_t bytes) { char* p = ws + off; off = (off + bytes + 255) & ~(size_t)255; return p; };
    u16*  Wt1f  = (u16*)alloc(2048ull * 512 * 2);
    u16*  Wt1b  = (u16*)alloc(2048ull * 512 * 2);
    u16*  Wt2f  = (u16*)alloc(2048ull * 1024 * 2);
    u16*  Wt2b  = (u16*)alloc(2048ull * 1024 * 2);
    u16*  Ut1f  = (u16*)alloc(2048ull * 512 * 2);
    u16*  Ut1b  = (u16*)alloc(2048ull * 512 * 2);
    u16*  Ut2f  = (u16*)alloc(2048ull * 512 * 2);
    u16*  Ut2b  = (u16*)alloc(2048ull * 512 * 2);
    int*  maskb = (int*)alloc(16384ull * 4);
    // per-wave flags: 2 dirs x 4 waves x 32 slices = 256 u32 (1 KB)
    u32*  flags = (u32*)alloc(1024);
    // h exchange: 2 slots x 2 dirs x 64 x 512 bf16 = 256 KB (never read before
    // write: step 0 consumes zero registers, so no zero-init needed)
    u16*  hg    = (u16*)alloc(2ull * 2 * 64 * 512 * 2);
    _Float16* xzf = (_Float16*)alloc(16384ull * 2048 * 2);
    _Float16* xzb = (_Float16*)alloc(16384ull * 2048 * 2);
    (void)ws_size; (void)in_sizes; (void)n_in; (void)out_size;
    const int initN = 256;  // flag words only

    // prep
    mask_kernel<<<dim3(16384), dim3(64), 0, stream>>>(X, maskb);
    cast_bf16_kernel<<<dim3(8192), dim3(256), 0, stream>>>(X, Xbf, 16384 * 512);
    transpose_cast_kernel<<<dim3(64, 16), dim3(32, 8), 0, stream>>>(Wf1, Wt1f, 512, 2048);
    transpose_cast_kernel<<<dim3(64, 16), dim3(32, 8), 0, stream>>>(Wb1, Wt1b, 512, 2048);
    transpose_cast_kernel<<<dim3(64, 32), dim3(32, 8), 0, stream>>>(Wf2, Wt2f, 1024, 2048);
    transpose_cast_kernel<<<dim3(64, 32), dim3(32, 8), 0, stream>>>(Wb2, Wt2b, 1024, 2048);
    transpose_cast_kernel<<<dim3(64, 16), dim3(32, 8), 0, stream>>>(Uf1, Ut1f, 512, 2048);
    transpose_cast_kernel<<<dim3(64, 16), dim3(32, 8), 0, stream>>>(Ub1, Ut1b, 512, 2048);
    transpose_cast_kernel<<<dim3(64, 16), dim3(32, 8), 0, stream>>>(Uf2, Ut2f, 512, 2048);
    transpose_cast_kernel<<<dim3(64, 16), dim3(32, 8), 0, stream>>>(Ub2, Ut2b, 512, 2048);

    // layer 1
    gemm_xz_kernel<<<dim3(64, 16), dim3(256), 0, stream>>>(Xbf, Wt1f, bf1, xzf, 512);
    gemm_xz_kernel<<<dim3(64, 16), dim3(256), 0, stream>>>(Xbf, Wt1b, bb1, xzb, 512);
    init_rec_kernel<<<dim3(1), dim3(256), 0, stream>>>(flags, initN);
    lstm_rec11_kernel<<<dim3(32, 2), dim3(256), 0, stream>>>(
        xzf, xzb, Ut1f, Ut1b, maskb, flags, hg, y1bf, nullptr, nullptr);

    // layer 2
    gemm_xz_kernel<<<dim3(64, 16), dim3(256), 0, stream>>>(y1bf, Wt2f, bf2, xzf, 1024);
    gemm_xz_kernel<<<dim3(64, 16), dim3(256), 0, stream>>>(y1bf, Wt2b, bb2, xzb, 1024);
    init_rec_kernel<<<dim3(1), dim3(256), 0, stream>>>(flags, initN);
    lstm_rec11_kernel<<<dim3(32, 2), dim3(256), 0, stream>>>(
        xzf, xzb, Ut2f, Ut2b, maskb, flags, hg, nullptr, out, out + 16777216);
}